// Round 7
// baseline (436.695 us; speedup 1.0000x reference)
//
#include <hip/hip_runtime.h>

// ---------------------------------------------------------------------------
// Weight transpose: w[o][c][k] -> wT[(k*ci + c)*co + o]  (o contiguous so the
// compute kernel's uniform weight reads merge into s_load_dwordx4/x8).
// ---------------------------------------------------------------------------
struct WtArgs { const float* src[6]; int co[6], ci[6], k2[6], dstoff[6]; };

__global__ __launch_bounds__(256)
void transpose_weights(WtArgs a, float* __restrict__ dst0)
{
    const int L = blockIdx.x;
    const float* __restrict__ s = a.src[L];
    float* __restrict__ d = dst0 + a.dstoff[L];
    const int co = a.co[L], ci = a.ci[L], k2 = a.k2[L];
    const int n = co * ci * k2;
    for (int i = threadIdx.x; i < n; i += 256) {
        int k = i % k2;
        int c = (i / k2) % ci;
        int o = i / (k2 * ci);
        d[(k * ci + c) * co + o] = s[i];
    }
}

// ---------------------------------------------------------------------------
// Deformable conv: one block per image. Image staged in LDS as float4
// channel-groups [c4][hw] (CIN%4==0) or scalar [hw] (CIN==1). Weights via
// wave-uniform scalar loads from wT[(k*CIN+c)*COUT+o]. Work decomposition:
// thread = (k-segment g, phase-pixel q); each thread handles PPB pixels
// {q, q+PH, ...} for its k-range. KSEG>1 partials reduced deterministically
// via sequenced adds into a bias-initialized LDS out-buffer.
// x: [B][CIN][H*W]   y: [B][COUT][HO*WO]
// ---------------------------------------------------------------------------
template<int CIN, int COUT, int K, int H, int W, int HO, int WO,
         int KSEG, int PPB, int NT, int KUNROLL>
__global__ __launch_bounds__(NT, (NT + 255) / 256)
void deform2(const float* __restrict__ x, const float* __restrict__ off,
             const float* __restrict__ wT, const float* __restrict__ bias,
             float* __restrict__ y)
{
    constexpr int K2 = K * K, HW = H * W, P = HO * WO;
    constexpr int PH = (P + PPB - 1) / PPB;             // pixels per phase
    constexpr int PW = ((PH + 63) / 64) * 64;           // wave-aligned
    constexpr int KLEN = (K2 + KSEG - 1) / KSEG;
    constexpr int PSTR = (COUT % 2) ? COUT : COUT + 1;  // odd stride
    constexpr int C4 = (CIN + 3) / 4;
    static_assert(KSEG * PW <= NT, "thread shortfall");
    static_assert(KSEG == 1 || KSEG * PW == NT, "exact fit required");

    __shared__ __align__(16) float simg[(CIN == 1) ? HW : C4 * HW * 4];
    __shared__ float outb[(KSEG > 1) ? P * PSTR : 1];

    const int tid = threadIdx.x;
    const int b   = blockIdx.x;
    const float* xb = x + (size_t)b * CIN * HW;

    // ---- stage image ----
    if constexpr (CIN == 1) {
        for (int i = tid; i < HW; i += NT) simg[i] = xb[i];
    } else {
        for (int i = tid; i < CIN * HW; i += NT) {
            int c = i / HW, hw = i - c * HW;
            simg[((c >> 2) * HW + hw) * 4 + (c & 3)] = xb[i];
        }
    }
    if constexpr (KSEG > 1) {
        for (int i = tid; i < P * COUT; i += NT) {
            int p = i / COUT, o = i - p * COUT;
            outb[p * PSTR + o] = bias[o];
        }
    }
    __syncthreads();

    const int g = tid / PW;               // wave-uniform k-segment id
    const int q = tid - g * PW;           // phase-pixel index

    int pix[PPB]; bool act[PPB]; int pcl[PPB]; int hoA[PPB], woA[PPB];
#pragma unroll
    for (int i = 0; i < PPB; ++i) {
        pix[i] = q + i * PH;
        act[i] = (q < PH) && (pix[i] < P);
        pcl[i] = act[i] ? pix[i] : 0;
        hoA[i] = pcl[i] / WO;
        woA[i] = pcl[i] - hoA[i] * WO;
    }

    float acc[PPB][COUT];
#pragma unroll
    for (int i = 0; i < PPB; ++i)
#pragma unroll
        for (int o = 0; o < COUT; ++o)
            acc[i][o] = (KSEG == 1) ? bias[o] : 0.f;

    if (g < KSEG) {
        const int kb = g * KLEN;
        float ndy[PPB], ndx[PPB];
        {
            const int kf = (kb < K2) ? kb : (K2 - 1);
#pragma unroll
            for (int i = 0; i < PPB; ++i) {
                ndy[i] = off[(2 * kf)     * P + pcl[i]];
                ndx[i] = off[(2 * kf + 1) * P + pcl[i]];
            }
        }

        auto kbody = [&](int j) {
            const int k  = kb + j;                      // wave-uniform
            const int kk = (k < K2) ? k : (K2 - 1);
            const int kku = __builtin_amdgcn_readfirstlane(kk);
            const int kyv = kku / K, kxv = kku - kyv * K;
            const float* __restrict__ wk = wT + kku * (CIN * COUT);
            const int kn = (k + 1 < K2) ? (k + 1) : (K2 - 1);

            float dyv[PPB], dxv[PPB];
#pragma unroll
            for (int i = 0; i < PPB; ++i) {
                dyv[i] = ndy[i]; dxv[i] = ndx[i];
                ndy[i] = off[(2 * kn)     * P + pcl[i]];
                ndx[i] = off[(2 * kn + 1) * P + pcl[i]];
            }

#pragma unroll
            for (int i = 0; i < PPB; ++i) {
                const float py = (float)(hoA[i] + kyv) + dyv[i];
                const float px = (float)(woA[i] + kxv) + dxv[i];
                const float y0f = floorf(py), x0f = floorf(px);
                const float wy = py - y0f, wx = px - x0f;
                const int y0 = (int)y0f, x0 = (int)x0f;
                const int y1 = y0 + 1,  x1 = x0 + 1;
                const bool vy0 = ((unsigned)y0 < (unsigned)H);
                const bool vy1 = ((unsigned)y1 < (unsigned)H);
                const bool vx0 = ((unsigned)x0 < (unsigned)W);
                const bool vx1 = ((unsigned)x1 < (unsigned)W);
                const int cy0 = min(max(y0, 0), H - 1) * W;
                const int cy1 = min(max(y1, 0), H - 1) * W;
                const int cx0 = min(max(x0, 0), W - 1);
                const int cx1 = min(max(x1, 0), W - 1);
                float w00 = (vy0 && vx0) ? (1.f - wy) * (1.f - wx) : 0.f;
                float w01 = (vy0 && vx1) ? (1.f - wy) * wx         : 0.f;
                float w10 = (vy1 && vx0) ? wy * (1.f - wx)         : 0.f;
                float w11 = (vy1 && vx1) ? wy * wx                 : 0.f;
                if constexpr (K2 % KSEG != 0) {
                    const float kv = (k < K2) ? 1.f : 0.f;   // masked tail
                    w00 *= kv; w01 *= kv; w10 *= kv; w11 *= kv;
                }
                const int i00 = cy0 + cx0, i01 = cy0 + cx1;
                const int i10 = cy1 + cx0, i11 = cy1 + cx1;

                if constexpr (CIN == 1) {
                    const float sa = fmaf(w00, simg[i00], fmaf(w01, simg[i01],
                                     fmaf(w10, simg[i10], w11 * simg[i11])));
#pragma unroll
                    for (int o = 0; o < COUT; ++o)
                        acc[i][o] = fmaf(wk[o], sa, acc[i][o]);
                } else {
                    const float4* __restrict__ s4 = (const float4*)simg;
#pragma unroll
                    for (int c4 = 0; c4 < C4; ++c4) {
                        const float4 v00 = s4[c4 * HW + i00];
                        const float4 v01 = s4[c4 * HW + i01];
                        const float4 v10 = s4[c4 * HW + i10];
                        const float4 v11 = s4[c4 * HW + i11];
                        float4 sa;
                        sa.x = fmaf(w00, v00.x, fmaf(w01, v01.x, fmaf(w10, v10.x, w11 * v11.x)));
                        sa.y = fmaf(w00, v00.y, fmaf(w01, v01.y, fmaf(w10, v10.y, w11 * v11.y)));
                        sa.z = fmaf(w00, v00.z, fmaf(w01, v01.z, fmaf(w10, v10.z, w11 * v11.z)));
                        sa.w = fmaf(w00, v00.w, fmaf(w01, v01.w, fmaf(w10, v10.w, w11 * v11.w)));
                        const float* __restrict__ wc = wk + (c4 * 4) * COUT;
#pragma unroll
                        for (int o = 0; o < COUT; ++o) acc[i][o] = fmaf(wc[o], sa.x, acc[i][o]);
#pragma unroll
                        for (int o = 0; o < COUT; ++o) acc[i][o] = fmaf(wc[COUT + o], sa.y, acc[i][o]);
#pragma unroll
                        for (int o = 0; o < COUT; ++o) acc[i][o] = fmaf(wc[2 * COUT + o], sa.z, acc[i][o]);
#pragma unroll
                        for (int o = 0; o < COUT; ++o) acc[i][o] = fmaf(wc[3 * COUT + o], sa.w, acc[i][o]);
                    }
                }
            }
        };

        if constexpr (KUNROLL == 2) {
#pragma unroll 2
            for (int j = 0; j < KLEN; ++j) kbody(j);
        } else {
#pragma unroll 1
            for (int j = 0; j < KLEN; ++j) kbody(j);
        }
    }

    // ---- store ----
    if constexpr (KSEG == 1) {
        float* yb = y + (size_t)b * COUT * P;
#pragma unroll
        for (int i = 0; i < PPB; ++i)
            if (act[i])
#pragma unroll
                for (int o = 0; o < COUT; ++o)
                    yb[o * P + pix[i]] = fmaxf(acc[i][o], 0.f);
    } else {
        // deterministic sequenced reduction into outb
        for (int gg = 0; gg < KSEG; ++gg) {
            if (g == gg) {
#pragma unroll
                for (int i = 0; i < PPB; ++i)
                    if (act[i])
#pragma unroll
                        for (int o = 0; o < COUT; ++o)
                            outb[pix[i] * PSTR + o] += acc[i][o];
            }
            __syncthreads();
        }
        float* yb = y + (size_t)b * COUT * P;
        for (int i = tid; i < COUT * P; i += NT) {
            int o = i / P, p = i - o * P;
            yb[i] = fmaxf(outb[p * PSTR + o], 0.f);
        }
    }
}

// ---------------------------------------------------------------------------
// Fused head: perm gather + FC(676->256) + ReLU + FC(256->10).
// 64 blocks x 256 threads; each block handles 4 batch rows.
// ---------------------------------------------------------------------------
__global__ __launch_bounds__(256)
void fc_head(const float* __restrict__ x6, const float* __restrict__ w7,
             const float* __restrict__ b7, const float* __restrict__ w8,
             const float* __restrict__ b8, const int* __restrict__ perm,
             float* __restrict__ out)
{
    constexpr int BPB = 4;
    constexpr int F   = 676;
    __shared__ float sx[BPB][F];
    __shared__ float sh[BPB][256];

    const int tid = threadIdx.x;
    const int b0  = blockIdx.x * BPB;

    for (int i = tid; i < BPB * F; i += 256) {
        int bb = i / F, f = i - bb * F;
        int c = f / 169, p = f - c * 169;
        sx[bb][f] = x6[(size_t)(b0 + bb) * F + c * 169 + perm[p]];
    }
    __syncthreads();

    float acc[BPB];
#pragma unroll
    for (int bb = 0; bb < BPB; ++bb) acc[bb] = b7[tid];
#pragma unroll 4
    for (int i = 0; i < F; ++i) {
        const float wv = w7[i * 256 + tid];
#pragma unroll
        for (int bb = 0; bb < BPB; ++bb)
            acc[bb] = fmaf(sx[bb][i], wv, acc[bb]);
    }
#pragma unroll
    for (int bb = 0; bb < BPB; ++bb) sh[bb][tid] = fmaxf(acc[bb], 0.f);
    __syncthreads();

    if (tid < BPB * 10) {
        int bb = tid / 10, t = tid - bb * 10;
        float a = b8[t];
#pragma unroll 8
        for (int j = 0; j < 256; ++j)
            a = fmaf(sh[bb][j], w8[j * 10 + t], a);
        out[(size_t)(b0 + bb) * 10 + t] = a;
    }
}

// ---------------------------------------------------------------------------
extern "C" void kernel_launch(void* const* d_in, const int* in_sizes, int n_in,
                              void* d_out, int out_size, void* d_ws, size_t ws_size,
                              hipStream_t stream)
{
    const float* x    = (const float*)d_in[0];
    const float* off1 = (const float*)d_in[1];
    const float* w1   = (const float*)d_in[2];
    const float* b1   = (const float*)d_in[3];
    const float* off2 = (const float*)d_in[4];
    const float* w2   = (const float*)d_in[5];
    const float* b2   = (const float*)d_in[6];
    const float* off3 = (const float*)d_in[7];
    const float* w3   = (const float*)d_in[8];
    const float* b3   = (const float*)d_in[9];
    const float* off4 = (const float*)d_in[10];
    const float* w4   = (const float*)d_in[11];
    const float* b4   = (const float*)d_in[12];
    const float* off5 = (const float*)d_in[13];
    const float* w5   = (const float*)d_in[14];
    const float* b5   = (const float*)d_in[15];
    const float* off6 = (const float*)d_in[16];
    const float* w6   = (const float*)d_in[17];
    const float* b6   = (const float*)d_in[18];
    const float* w7   = (const float*)d_in[19];
    const float* b7   = (const float*)d_in[20];
    const float* w8   = (const float*)d_in[21];
    const float* b8   = (const float*)d_in[22];
    const int*   perm = (const int*)d_in[23];
    float* out = (float*)d_out;

    // ws layout (floats), identical footprint to the proven layout:
    // wt @0 (33,792), buf0 @33,792 (3,936,256), buf1 after (6,889,472)
    const int woff[6] = {0, 144, 4752, 17552, 30096, 33296};
    float* ws   = (float*)d_ws;
    float* wt   = ws;
    float* buf0 = ws + 33792;
    float* buf1 = buf0 + 3936256;

    float* a1 = buf0;   // 256*16*961
    float* a2 = buf1;   // 256*32*841
    float* a3 = buf0;   // 256*16*625
    float* a4 = buf1;   // 256*16*361
    float* a5 = buf0;   // 256*8*225
    float* a6 = buf1;   // 256*4*169

    WtArgs wa;
    wa.src[0] = w1; wa.src[1] = w2; wa.src[2] = w3;
    wa.src[3] = w4; wa.src[4] = w5; wa.src[5] = w6;
    const int cos[6] = {16, 32, 16, 16, 8, 4};
    const int cis[6] = {1, 16, 32, 16, 16, 8};
    const int k2s[6] = {9, 9, 25, 49, 25, 9};
    for (int i = 0; i < 6; ++i) {
        wa.co[i] = cos[i]; wa.ci[i] = cis[i];
        wa.k2[i] = k2s[i]; wa.dstoff[i] = woff[i];
    }
    transpose_weights<<<dim3(6), dim3(256), 0, stream>>>(wa, wt);

    const dim3 grid(256);
    // <CIN,COUT,K,H,W,HO,WO, KSEG,PPB,NT,KUNROLL>
    deform2< 1, 16, 3, 33, 33, 31, 31, 1, 1, 1024, 1><<<grid, dim3(1024), 0, stream>>>(x,  off1, wt + woff[0], b1, a1);
    deform2<16, 32, 3, 31, 31, 29, 29, 1, 1, 1024, 2><<<grid, dim3(1024), 0, stream>>>(a1, off2, wt + woff[1], b2, a2);
    deform2<32, 16, 5, 29, 29, 25, 25, 3, 2,  960, 1><<<grid, dim3(960),  0, stream>>>(a2, off3, wt + woff[2], b3, a3);
    deform2<16, 16, 7, 25, 25, 19, 19, 5, 2,  960, 1><<<grid, dim3(960),  0, stream>>>(a3, off4, wt + woff[3], b4, a4);
    deform2<16,  8, 5, 19, 19, 15, 15, 4, 1, 1024, 1><<<grid, dim3(1024), 0, stream>>>(a4, off5, wt + woff[4], b5, a5);
    deform2< 8,  4, 3, 15, 15, 13, 13, 5, 1,  960, 1><<<grid, dim3(960),  0, stream>>>(a5, off6, wt + woff[5], b6, a6);

    fc_head<<<dim3(64), dim3(256), 0, stream>>>(a6, w7, b7, w8, b8, perm, out);
}